// Round 4
// baseline (407.862 us; speedup 1.0000x reference)
//
#include <hip/hip_runtime.h>
#include <stdint.h>

#define EMB 768
#define SEQ 2048
#define BATCH 4
#define NHEADS 12
#define HDIM 64
#define FFDIM 3072
#define NTOK (BATCH*SEQ)
#define LNEPS 1e-5f
#define QSCALE 0.1803368801111137f  /* 0.125 * log2(e) */

typedef __attribute__((ext_vector_type(8))) short bf16x8;
typedef __attribute__((ext_vector_type(4))) float f32x4;
typedef __attribute__((ext_vector_type(16))) float f32x16;

__device__ __forceinline__ uint16_t f2bf(float f){
  union { float f; uint32_t u; } v; v.f = f;
  uint32_t r = v.u + 0x7fffu + ((v.u >> 16) & 1u);
  return (uint16_t)(r >> 16);
}
// pack two f32 -> one u32 of 2 bf16 (RNE), single instruction
__device__ __forceinline__ uint32_t cvt_pk_bf16(float lo, float hi){
  uint32_t d;
  asm("v_cvt_pk_bf16_f32 %0, %1, %2" : "=v"(d) : "v"(lo), "v"(hi));
  return d;
}

// async global->LDS, 16B per lane. LDS dest = wave-uniform base + lane*16.
typedef __attribute__((address_space(3))) uint32_t lds32_t;
typedef __attribute__((address_space(1))) const uint32_t glb32_t;
__device__ __forceinline__ void gload16(const void* g, void* l){
  __builtin_amdgcn_global_load_lds((glb32_t*)(uintptr_t)g,
                                   (lds32_t*)(uintptr_t)l, 16, 0, 0);
}

// ---------- merged fp32 [K,N] -> bf16 [N,K] weight convert+transpose ----------
struct TPtrs { const float* src[6]; uint16_t* dst[6]; };
__global__ __launch_bounds__(256) void transpose_all(TPtrs tp){
  int idx = blockIdx.x;
  int which, bx, by, K, N;
  if (idx < 2304){ which = idx/576; int l = idx - which*576; bx = l%24; by = l/24; K = 768;  N = 768;  }
  else if (idx < 4608){ which = 4; int l = idx-2304; bx = l%96; by = l/96; K = 768;  N = 3072; }
  else { which = 5; int l = idx-4608; bx = l%24; by = l/24; K = 3072; N = 768;  }
  const float* w = tp.src[which];
  uint16_t* wt   = tp.dst[which];
  __shared__ uint16_t tile[32][33];
  int n0 = bx*32, k0 = by*32;
  #pragma unroll
  for (int i=0;i<4;i++){
    int k = threadIdx.y + i*8;
    tile[k][threadIdx.x] = f2bf(w[(size_t)(k0+k)*N + n0 + threadIdx.x]);
  }
  __syncthreads();
  #pragma unroll
  for (int i=0;i<4;i++){
    int n = threadIdx.y + i*8;
    wt[(size_t)(n0+n)*K + k0 + threadIdx.x] = tile[threadIdx.x][n];
  }
}

// ---------- LayerNorm: fp32 in -> bf16 out, one wave per row ----------
__global__ __launch_bounds__(256) void ln_kernel(const float* __restrict__ x,
    const float* __restrict__ sc, const float* __restrict__ sh,
    uint16_t* __restrict__ out)
{
  int row = blockIdx.x*4 + (threadIdx.x>>6);
  int ln = threadIdx.x & 63;
  const float4* xr = (const float4*)(x + (size_t)row*EMB);
  float4 v0 = xr[ln], v1 = xr[64+ln], v2 = xr[128+ln];
  float s  = v0.x+v0.y+v0.z+v0.w + v1.x+v1.y+v1.z+v1.w + v2.x+v2.y+v2.z+v2.w;
  float s2 = v0.x*v0.x+v0.y*v0.y+v0.z*v0.z+v0.w*v0.w
           + v1.x*v1.x+v1.y*v1.y+v1.z*v1.z+v1.w*v1.w
           + v2.x*v2.x+v2.y*v2.y+v2.z*v2.z+v2.w*v2.w;
  #pragma unroll
  for (int off=1;off<64;off<<=1){ s += __shfl_xor(s,off); s2 += __shfl_xor(s2,off); }
  float mean = s*(1.f/768.f);
  float var  = s2*(1.f/768.f) - mean*mean;
  float rstd = rsqrtf(var + LNEPS);
  uint16_t* orow = out + (size_t)row*EMB;
  float4 vv[3] = {v0,v1,v2};
  #pragma unroll
  for (int i=0;i<3;i++){
    int c = (i*64+ln)*4;
    ushort4 o4;
    o4.x = f2bf((vv[i].x-mean)*rstd*sc[c+0] + sh[c+0]);
    o4.y = f2bf((vv[i].y-mean)*rstd*sc[c+1] + sh[c+1]);
    o4.z = f2bf((vv[i].z-mean)*rstd*sc[c+2] + sh[c+2]);
    o4.w = f2bf((vv[i].w-mean)*rstd*sc[c+3] + sh[c+3]);
    *(ushort4*)(orow + c) = o4;
  }
}

// ---------- GEMM: C[M,N] = A[M,K](bf16) * Bt[N,K](bf16)^T ----------
// Tile TM x 128, double-buffered async LDS staging, one barrier per K-iter.
// MODE 0: store bf16 (z==0 Q scaled by QSCALE; z==2 -> V transposed [b][h][d][s])
// MODE 1: +bias +fp32 residual -> fp32
// MODE 2: +bias, gelu -> bf16
// MODE 3: +bias +fp32 residual -> fp32 (final out)
template<int MODE, int TM>
__global__ __launch_bounds__(256, 4) void gemm_bt(const uint16_t* __restrict__ A,
    const uint16_t* __restrict__ Bt0,
    const float* __restrict__ bias,
    const float* __restrict__ resid,
    void* __restrict__ outp,
    uint16_t* __restrict__ vt_out,
    int N, int K, long bt_zstride, long out_zstride)
{
  constexpr int MI = TM/32;             // m-frags per wave
  __shared__ __align__(16) uint16_t As[2][TM][32];
  __shared__ __align__(16) uint16_t Bs[2][128][32];
  const uint16_t* Bt = Bt0 + (size_t)blockIdx.z * bt_zstride;
  int tid = threadIdx.x;
  int wave = tid>>6, ln = tid&63, lane16 = ln&15, quad = ln>>4;
  int m0 = blockIdx.x*TM, n0 = blockIdx.y*128;
  int wm = (wave>>1)*(MI*16), wn = (wave&1)*64;
  f32x4 zf = {0.f,0.f,0.f,0.f};
  f32x4 acc[MI][4];
  #pragma unroll
  for (int i=0;i<MI;i++)
    #pragma unroll
    for (int j=0;j<4;j++) acc[i][j]=zf;
  int ar = tid>>2;
  int ac = (tid&3)*8;
  const uint16_t* Arow0 = A  + (size_t)(m0+ar)*K    + ac;
  const uint16_t* Arow1 = A  + (size_t)(m0+ar+64)*K + ac;   // TM==128 only
  const uint16_t* Brow0 = Bt + (size_t)(n0+ar)*K    + ac;
  const uint16_t* Brow1 = Bt + (size_t)(n0+ar+64)*K + ac;

  auto stage = [&](int buf, int k0){
    char* lA = (char*)&As[buf][0][0] + wave*1024;
    char* lB = (char*)&Bs[buf][0][0] + wave*1024;
    gload16(Arow0 + k0, lA);
    if (TM==128) gload16(Arow1 + k0, lA + 4096);
    gload16(Brow0 + k0, lB);
    gload16(Brow1 + k0, lB + 4096);
  };

  int niter = K>>5;
  stage(0, 0);
  for (int s=0; s<niter; s++){
    __syncthreads();                    // drains staging of buf s&1
    if (s+1 < niter) stage((s+1)&1, (s+1)<<5);
    int buf = s&1;
    bf16x8 af[MI], bfr[4];
    #pragma unroll
    for (int mi=0;mi<MI;mi++) af[mi]  = *(const bf16x8*)&As[buf][wm+mi*16+lane16][quad*8];
    #pragma unroll
    for (int ni=0;ni<4;ni++)  bfr[ni] = *(const bf16x8*)&Bs[buf][wn+ni*16+lane16][quad*8];
    #pragma unroll
    for (int mi=0;mi<MI;mi++)
      #pragma unroll
      for (int ni=0;ni<4;ni++)
        acc[mi][ni] = __builtin_amdgcn_mfma_f32_16x16x32_bf16(af[mi], bfr[ni], acc[mi][ni], 0,0,0);
  }
  if (MODE==0 && blockIdx.z==2){
    #pragma unroll
    for (int mi=0;mi<MI;mi++){
      int mrow0 = m0 + wm + mi*16 + quad*4;
      int bb = mrow0 >> 11, s = mrow0 & 2047;
      #pragma unroll
      for (int ni=0;ni<4;ni++){
        int ncol = n0 + wn + ni*16 + lane16;
        int hh = ncol >> 6, dd = ncol & 63;
        ushort4 o4 = { f2bf(acc[mi][ni][0]), f2bf(acc[mi][ni][1]),
                       f2bf(acc[mi][ni][2]), f2bf(acc[mi][ni][3]) };
        *(ushort4*)(vt_out + ((size_t)((bb*NHEADS+hh)*HDIM + dd))*SEQ + s) = o4;
      }
    }
    return;
  }
  float oscale = (MODE==0 && blockIdx.z==0) ? QSCALE : 1.0f;
  #pragma unroll
  for (int mi=0;mi<MI;mi++){
    #pragma unroll
    for (int r=0;r<4;r++){
      int mrow = m0 + wm + mi*16 + quad*4 + r;
      #pragma unroll
      for (int ni=0;ni<4;ni++){
        int ncol = n0 + wn + ni*16 + lane16;
        float vv = acc[mi][ni][r];
        size_t idx = (size_t)mrow*N + ncol;
        if (MODE==0){
          ((uint16_t*)outp)[(size_t)blockIdx.z*out_zstride + idx] = f2bf(vv*oscale);
        } else if (MODE==1){
          ((float*)outp)[idx] = vv + bias[ncol] + resid[idx];
        } else if (MODE==2){
          float t = vv + bias[ncol];
          float u = 1.5957691216057308f*(t + 0.044715f*t*t*t);
          ((uint16_t*)outp)[idx] = f2bf(t / (1.f + __expf(-u)));
        } else {
          ((float*)outp)[idx] = vv + bias[ncol] + resid[idx];
        }
      }
    }
  }
}

// ---------- Flash attention v7: kv-parity split, direct-from-L2, no staging --
// Round-3 post-mortem: 1536 waves on 1024 SIMDs (1.5/SIMD) left the per-step
// serial chain (MFMA->shfl->exp2->shfl->MFMA, ~900cy) exposed; staging
// pipeline depth was irrelevant. Fix = more waves + barrier-free loop:
//  * Block (128 thr) = one 32-row q-slice pair {sp, 63-sp} of one (b,h).
//    Grid 1536 blocks * 2 waves = 3072 waves = 3 waves/SIMD.
//  * The 2 waves process the SAME 32 q-rows, ALTERNATING kv-tiles (parity
//    split), each with private online-softmax state (m,l,O); merged once per
//    slice via a small LDS combine (standard split-kv rescale). Only 2
//    __syncthreads per slice vs barrier-per-step before.
//  * K/V working set is L2-resident by XCD clustering (3MB/XCD < 4MB), so
//    LDS staging is dropped entirely (guide mistake #7): MFMA fragments are
//    loaded straight from global as per-lane 16B reads; each K/V tile row is
//    one aligned 128B line, fully covered by the 4 dm / 4 ks loads. The loop
//    body has no stores and no barriers -> compiler pipelines loads freely,
//    and 3 waves/SIMD hide the L2-hit latency.
// Slice-pair step counts: (sp/2+1) + ((63-sp)/2+1) = 33, uniform per block.
__global__ __launch_bounds__(128, 3) void attn_kernel(const uint16_t* __restrict__ q,
    const uint16_t* __restrict__ k, const uint16_t* __restrict__ vt,
    uint16_t* __restrict__ ctx)
{
  __shared__ float cmb[64][35];   // [lane][m,l,o0[16],o1[16]] (pad->35: conflict-free)
  int tid = threadIdx.x;
  int wv = tid>>6, ln = tid&63, l32 = ln&31, h5 = ln>>5;
  // XCD-clustered decode: per-XCD K/V working set = 6 groups x 512KB = 3MB
  int id  = blockIdx.x;        // 0..1535
  int xcd = id & 7;
  int s_  = id >> 3;           // 0..191
  int sp  = s_ & 31;           // slice-pair index 0..31
  int g   = xcd*6 + (s_ >> 5); // (b,h) group 0..47, one XCD per group
  int h   = g % NHEADS, b = g / NHEADS;

  // per-lane fragment row pointers (K: row=kv, V^T: row=d)
  const uint16_t* krow = k  + ((size_t)(b*SEQ) + l32)*EMB + h*HDIM + h5*8;
  const uint16_t* vrow = vt + ((size_t)((b*NHEADS + h)*HDIM + l32))*SEQ + h5*8;

  f32x16 o0, o1;               // O accum: col=q(l32), row=d-local
  float m_l, l_l;
  bf16x8 qb[4];                // Q B-operand frags: d = dm*16 + h5*8 + j
  int myq;

  auto compute = [&](int kv0, bool masked){
    const uint16_t* kA = krow + (size_t)kv0*EMB;
    const uint16_t* vA = vrow + kv0;
    // V fragments first: issue early, consumed only after softmax
    bf16x8 va[4][2];
    #pragma unroll
    for (int ks=0;ks<4;ks++){
      va[ks][0] = *(const bf16x8*)(vA + ks*16);            // d=l32,    kv=ks*16+h5*8+j
      va[ks][1] = *(const bf16x8*)(vA + 32*SEQ + ks*16);   // d=32+l32
    }
    // K fragments: A-operand row=kv(l32), k-slot = h5*8+j -> d = dm*16+h5*8+j
    bf16x8 kf0[4], kf1[4];
    #pragma unroll
    for (int dm=0;dm<4;dm++){
      kf0[dm] = *(const bf16x8*)(kA + dm*16);
      kf1[dm] = *(const bf16x8*)(kA + (size_t)32*EMB + dm*16);
    }
    f32x16 st0, st1;           // S^T: row=kv-local, col=q(l32)
    #pragma unroll
    for (int r=0;r<16;r++){ st0[r]=0.f; st1[r]=0.f; }
    __builtin_amdgcn_s_setprio(1);
    #pragma unroll
    for (int dm=0;dm<4;dm++){
      st0 = __builtin_amdgcn_mfma_f32_32x32x16_bf16(kf0[dm], qb[dm], st0, 0,0,0);
      st1 = __builtin_amdgcn_mfma_f32_32x32x16_bf16(kf1[dm], qb[dm], st1, 0,0,0);
    }
    __builtin_amdgcn_s_setprio(0);
    if (masked){
      #pragma unroll
      for (int r=0;r<16;r++){
        int kvr = kv0 + (r&3) + 8*(r>>2) + 4*h5;   // C row->kv mapping
        if (kvr      > myq) st0[r] = -1e30f;
        if (kvr + 32 > myq) st1[r] = -1e30f;
      }
    }
    // row max over own 32 values (tree), then combine with partner half
    float t[8];
    #pragma unroll
    for (int r=0;r<8;r++)
      t[r] = fmaxf(fmaxf(st0[r], st0[r+8]), fmaxf(st1[r], st1[r+8]));
    t[0]=fmaxf(t[0],t[4]); t[1]=fmaxf(t[1],t[5]);
    t[2]=fmaxf(t[2],t[6]); t[3]=fmaxf(t[3],t[7]);
    float cm = fmaxf(fmaxf(t[0],t[1]), fmaxf(t[2],t[3]));
    cm = fmaxf(cm, __shfl_xor(cm, 32));          // combine with partner half
    // defer-max (T13): rescale only when max grew by > 6 (log2 domain)
    if (!__all(cm - m_l <= 6.0f)){
      float mn = fmaxf(m_l, cm);
      float alpha = __builtin_amdgcn_exp2f(m_l - mn);
      l_l *= alpha;
      #pragma unroll
      for (int r=0;r<16;r++){ o0[r]*=alpha; o1[r]*=alpha; }
      m_l = mn;
    }
    #pragma unroll
    for (int r=0;r<16;r++){
      st0[r] = __builtin_amdgcn_exp2f(st0[r] - m_l);
      st1[r] = __builtin_amdgcn_exp2f(st1[r] - m_l);
    }
    float s0=0.f, s1=0.f, s2=0.f, s3=0.f;
    #pragma unroll
    for (int r=0;r<16;r+=4){
      s0 += st0[r+0] + st1[r+0];
      s1 += st0[r+1] + st1[r+1];
      s2 += st0[r+2] + st1[r+2];
      s3 += st0[r+3] + st1[r+3];
    }
    float rs = (s0+s1)+(s2+s3);
    rs += __shfl_xor(rs, 32);                    // own + partner in all lanes
    l_l += rs;
    // P -> bf16 B-operand frags pbv[ks]: k = h5*8+j -> kv = ks*16 + h5*8 + j.
    // Own regs cover rows (0,1,2,3)+4h5 and (8..11)+4h5 of each 16-row slice;
    // the other half lives in the partner lane (same q, h5^1) -> shfl_xor(32).
    bf16x8 pbv[4];
    #pragma unroll
    for (int ks=0;ks<4;ks++){
      const int bs = (ks&1)*8;
      uint32_t c0,c1,c2,c3;
      if (ks < 2){
        c0 = cvt_pk_bf16(st0[bs+0], st0[bs+1]);  // rows (0,1)+base+4h5
        c1 = cvt_pk_bf16(st0[bs+2], st0[bs+3]);  // rows (2,3)+base+4h5
        c2 = cvt_pk_bf16(st0[bs+4], st0[bs+5]);  // rows (8,9)+base+4h5
        c3 = cvt_pk_bf16(st0[bs+6], st0[bs+7]);  // rows (10,11)+base+4h5
      } else {
        c0 = cvt_pk_bf16(st1[bs+0], st1[bs+1]);
        c1 = cvt_pk_bf16(st1[bs+2], st1[bs+3]);
        c2 = cvt_pk_bf16(st1[bs+4], st1[bs+5]);
        c3 = cvt_pk_bf16(st1[bs+6], st1[bs+7]);
      }
      // h5=0 lane needs partner's c0,c1 (kv+4..7); h5=1 needs partner's c2,c3
      uint32_t ya = (uint32_t)__shfl_xor((int)(h5 ? c0 : c2), 32);
      uint32_t yb = (uint32_t)__shfl_xor((int)(h5 ? c1 : c3), 32);
      union { uint32_t u[4]; bf16x8 v; } pu;
      pu.u[0] = h5 ? ya : c0;
      pu.u[1] = h5 ? yb : c1;
      pu.u[2] = h5 ? c2 : ya;
      pu.u[3] = h5 ? c3 : yb;
      pbv[ks] = pu.v;
    }
    __builtin_amdgcn_s_setprio(1);
    #pragma unroll
    for (int ks=0;ks<4;ks++){
      // A=V^T: row=d-local(l32), k-slot = h5*8+j -> kv = ks*16+h5*8+j
      o0 = __builtin_amdgcn_mfma_f32_32x32x16_bf16(va[ks][0], pbv[ks], o0, 0,0,0);
      o1 = __builtin_amdgcn_mfma_f32_32x32x16_bf16(va[ks][1], pbv[ks], o1, 0,0,0);
    }
    __builtin_amdgcn_s_setprio(0);
  };

  // process one 32-row slice: waves split kv-tiles by parity, LDS-combine
  auto do_slice = [&](int sl, int si){
    myq = sl*32 + l32;
    const uint16_t* qrow = q + ((size_t)(b*SEQ + myq))*EMB + h*HDIM + h5*8;
    #pragma unroll
    for (int dm=0;dm<4;dm++) qb[dm] = *(const bf16x8*)(qrow + dm*16);
    #pragma unroll
    for (int r=0;r<16;r++){ o0[r]=0.f; o1[r]=0.f; }
    m_l = -3.0e38f; l_l = 0.f;
    int tdiag = sl >> 1;                       // diagonal kv-tile index
    // parity (wv^si): alternates which wave carries the odd step count
    for (int t = (wv ^ si) & 1; t <= tdiag; t += 2)
      compute(t*64, t == tdiag);
    if (wv == 1){
      cmb[ln][0] = m_l; cmb[ln][1] = l_l;
      #pragma unroll
      for (int r=0;r<16;r++){ cmb[ln][2+r] = o0[r]; cmb[ln][18+r] = o1[r]; }
    }
    __syncthreads();
    if (wv == 0){
      float m1 = cmb[ln][0], l1 = cmb[ln][1];
      float mn = fmaxf(m_l, m1);
      float a0 = __builtin_amdgcn_exp2f(m_l - mn);
      float a1 = __builtin_amdgcn_exp2f(m1 - mn);
      float inv = 1.0f / (l_l*a0 + l1*a1);
      // o reg r -> d = (r&3) + 8*(r>>2) + 4*h5  (+32 for o1), col q = myq
      uint16_t* crow = ctx + ((size_t)(b*SEQ + myq))*EMB + h*HDIM + 4*h5;
      #pragma unroll
      for (int rr=0; rr<4; rr++){
        ushort4 w0 = {
          f2bf((o0[4*rr+0]*a0 + cmb[ln][2+4*rr+0]*a1)*inv),
          f2bf((o0[4*rr+1]*a0 + cmb[ln][2+4*rr+1]*a1)*inv),
          f2bf((o0[4*rr+2]*a0 + cmb[ln][2+4*rr+2]*a1)*inv),
          f2bf((o0[4*rr+3]*a0 + cmb[ln][2+4*rr+3]*a1)*inv) };
        *(ushort4*)(crow + rr*8) = w0;
        ushort4 w1 = {
          f2bf((o1[4*rr+0]*a0 + cmb[ln][18+4*rr+0]*a1)*inv),
          f2bf((o1[4*rr+1]*a0 + cmb[ln][18+4*rr+1]*a1)*inv),
          f2bf((o1[4*rr+2]*a0 + cmb[ln][18+4*rr+2]*a1)*inv),
          f2bf((o1[4*rr+3]*a0 + cmb[ln][18+4*rr+3]*a1)*inv) };
        *(ushort4*)(crow + 32 + rr*8) = w1;
      }
    }
    __syncthreads();                           // protect cmb reuse by next slice
  };

  do_slice(sp, 0);
  do_slice(63 - sp, 1);
}

extern "C" void kernel_launch(void* const* d_in, const int* in_sizes, int n_in,
                              void* d_out, int out_size, void* d_ws, size_t ws_size,
                              hipStream_t stream) {
  const float* x     = (const float*)d_in[0];
  const float* ln1_s = (const float*)d_in[1];
  const float* ln1_b = (const float*)d_in[2];
  const float* wq    = (const float*)d_in[3];
  const float* wk    = (const float*)d_in[4];
  const float* wv    = (const float*)d_in[5];
  const float* wo    = (const float*)d_in[6];
  const float* bo    = (const float*)d_in[7];
  const float* ln2_s = (const float*)d_in[8];
  const float* ln2_b = (const float*)d_in[9];
  const float* w1    = (const float*)d_in[10];
  const float* b1    = (const float*)d_in[11];
  const float* w2    = (const float*)d_in[12];
  const float* b2    = (const float*)d_in[13];

  uint16_t* wqkv_t = (uint16_t*)d_ws;                 // 3 x [768][768]
  uint16_t* wo_t   = wqkv_t + 3*EMB*EMB;              // [768][768]
  uint16_t* w1_t   = wo_t   + EMB*EMB;                // [3072][768]
  uint16_t* w2_t   = w1_t   + (size_t)FFDIM*EMB;      // [768][3072]
  uint16_t* xn     = w2_t   + (size_t)EMB*FFDIM;      // [8192][768]
  uint16_t* qkv    = xn     + (size_t)NTOK*EMB;       // q,k normal; v slot unused
  uint16_t* ctx    = qkv    + (size_t)3*NTOK*EMB;     // [8192][768]
  uint16_t* hff    = qkv;                             // [8192][3072] overlays qkv+ctx
  float*    x1     = (float*)(ctx + (size_t)NTOK*EMB);// [8192][768] fp32
  uint16_t* vt     = (uint16_t*)(x1 + (size_t)NTOK*EMB); // [4][12][64][2048] V^T

  TPtrs tp;
  tp.src[0]=wq; tp.src[1]=wk; tp.src[2]=wv; tp.src[3]=wo; tp.src[4]=w1; tp.src[5]=w2;
  tp.dst[0]=wqkv_t; tp.dst[1]=wqkv_t+EMB*EMB; tp.dst[2]=wqkv_t+2*EMB*EMB;
  tp.dst[3]=wo_t; tp.dst[4]=w1_t; tp.dst[5]=w2_t;
  transpose_all<<<6912, dim3(32,8), 0, stream>>>(tp);

  ln_kernel<<<NTOK/4, 256, 0, stream>>>(x, ln1_s, ln1_b, xn);
  gemm_bt<0,128><<<dim3(NTOK/128, EMB/128, 3), 256, 0, stream>>>(
      xn, wqkv_t, nullptr, nullptr, qkv, vt, EMB, EMB,
      (long)EMB*EMB, (long)NTOK*EMB);
  attn_kernel<<<1536, 128, 0, stream>>>(
      qkv, qkv + (size_t)NTOK*EMB, vt, ctx);
  // proj: TM=64 -> grid 128x6 = 768 blocks (3/CU)
  gemm_bt<1,64><<<dim3(NTOK/64, EMB/128, 1), 256, 0, stream>>>(
      ctx, wo_t, bo, x, x1, nullptr, EMB, EMB, 0, 0);
  ln_kernel<<<NTOK/4, 256, 0, stream>>>(x1, ln2_s, ln2_b, xn);
  gemm_bt<2,128><<<dim3(NTOK/128, FFDIM/128, 1), 256, 0, stream>>>(
      xn, w1_t, b1, nullptr, hff, nullptr, FFDIM, EMB, 0, 0);
  // FFN2: TM=64 -> grid 128x6 = 768 blocks (3/CU)
  gemm_bt<3,64><<<dim3(NTOK/64, EMB/128, 1), 256, 0, stream>>>(
      hff, w2_t, b2, x1, d_out, nullptr, EMB, FFDIM, 0, 0);
}

// Round 5
// 385.334 us; speedup vs baseline: 1.0585x; 1.0585x over previous
//
#include <hip/hip_runtime.h>
#include <stdint.h>

#define EMB 768
#define SEQ 2048
#define BATCH 4
#define NHEADS 12
#define HDIM 64
#define FFDIM 3072
#define NTOK (BATCH*SEQ)
#define LNEPS 1e-5f
#define QSCALE 0.1803368801111137f  /* 0.125 * log2(e) */

typedef __attribute__((ext_vector_type(8))) short bf16x8;
typedef __attribute__((ext_vector_type(4))) float f32x4;
typedef __attribute__((ext_vector_type(16))) float f32x16;

__device__ __forceinline__ uint16_t f2bf(float f){
  union { float f; uint32_t u; } v; v.f = f;
  uint32_t r = v.u + 0x7fffu + ((v.u >> 16) & 1u);
  return (uint16_t)(r >> 16);
}
// pack two f32 -> one u32 of 2 bf16 (RNE), single instruction
__device__ __forceinline__ uint32_t cvt_pk_bf16(float lo, float hi){
  uint32_t d;
  asm("v_cvt_pk_bf16_f32 %0, %1, %2" : "=v"(d) : "v"(lo), "v"(hi));
  return d;
}

// async global->LDS, 16B per lane. LDS dest = wave-uniform base + lane*16.
typedef __attribute__((address_space(3))) uint32_t lds32_t;
typedef __attribute__((address_space(1))) const uint32_t glb32_t;
__device__ __forceinline__ void gload16(const void* g, void* l){
  __builtin_amdgcn_global_load_lds((glb32_t*)(uintptr_t)g,
                                   (lds32_t*)(uintptr_t)l, 16, 0, 0);
}

// inline-asm LDS read: compiler cannot see the global_load_lds -> ds_read
// dependency, so it cannot insert its serializing s_waitcnt vmcnt(0) (the
// round-2/3 stall). Ordering is enforced by OUR counted vmcnt + s_barrier.
// Discipline per guide rule #18: sched_barrier(0) fences + explicit lgkmcnt.
__device__ __forceinline__ bf16x8 lds_read16(const void* p){
  bf16x8 r; uint32_t off = (uint32_t)(uintptr_t)p;
  asm volatile("ds_read_b128 %0, %1" : "=v"(r) : "v"(off));
  return r;
}

// ---------- merged fp32 [K,N] -> bf16 [N,K] weight convert+transpose ----------
struct TPtrs { const float* src[6]; uint16_t* dst[6]; };
__global__ __launch_bounds__(256) void transpose_all(TPtrs tp){
  int idx = blockIdx.x;
  int which, bx, by, K, N;
  if (idx < 2304){ which = idx/576; int l = idx - which*576; bx = l%24; by = l/24; K = 768;  N = 768;  }
  else if (idx < 4608){ which = 4; int l = idx-2304; bx = l%96; by = l/96; K = 768;  N = 3072; }
  else { which = 5; int l = idx-4608; bx = l%24; by = l/24; K = 3072; N = 768;  }
  const float* w = tp.src[which];
  uint16_t* wt   = tp.dst[which];
  __shared__ uint16_t tile[32][33];
  int n0 = bx*32, k0 = by*32;
  #pragma unroll
  for (int i=0;i<4;i++){
    int k = threadIdx.y + i*8;
    tile[k][threadIdx.x] = f2bf(w[(size_t)(k0+k)*N + n0 + threadIdx.x]);
  }
  __syncthreads();
  #pragma unroll
  for (int i=0;i<4;i++){
    int n = threadIdx.y + i*8;
    wt[(size_t)(n0+n)*K + k0 + threadIdx.x] = tile[threadIdx.x][n];
  }
}

// ---------- LayerNorm: fp32 in -> bf16 out, one wave per row ----------
__global__ __launch_bounds__(256) void ln_kernel(const float* __restrict__ x,
    const float* __restrict__ sc, const float* __restrict__ sh,
    uint16_t* __restrict__ out)
{
  int row = blockIdx.x*4 + (threadIdx.x>>6);
  int ln = threadIdx.x & 63;
  const float4* xr = (const float4*)(x + (size_t)row*EMB);
  float4 v0 = xr[ln], v1 = xr[64+ln], v2 = xr[128+ln];
  float s  = v0.x+v0.y+v0.z+v0.w + v1.x+v1.y+v1.z+v1.w + v2.x+v2.y+v2.z+v2.w;
  float s2 = v0.x*v0.x+v0.y*v0.y+v0.z*v0.z+v0.w*v0.w
           + v1.x*v1.x+v1.y*v1.y+v1.z*v1.z+v1.w*v1.w
           + v2.x*v2.x+v2.y*v2.y+v2.z*v2.z+v2.w*v2.w;
  #pragma unroll
  for (int off=1;off<64;off<<=1){ s += __shfl_xor(s,off); s2 += __shfl_xor(s2,off); }
  float mean = s*(1.f/768.f);
  float var  = s2*(1.f/768.f) - mean*mean;
  float rstd = rsqrtf(var + LNEPS);
  uint16_t* orow = out + (size_t)row*EMB;
  float4 vv[3] = {v0,v1,v2};
  #pragma unroll
  for (int i=0;i<3;i++){
    int c = (i*64+ln)*4;
    ushort4 o4;
    o4.x = f2bf((vv[i].x-mean)*rstd*sc[c+0] + sh[c+0]);
    o4.y = f2bf((vv[i].y-mean)*rstd*sc[c+1] + sh[c+1]);
    o4.z = f2bf((vv[i].z-mean)*rstd*sc[c+2] + sh[c+2]);
    o4.w = f2bf((vv[i].w-mean)*rstd*sc[c+3] + sh[c+3]);
    *(ushort4*)(orow + c) = o4;
  }
}

// ---------- GEMM: C[M,N] = A[M,K](bf16) * Bt[N,K](bf16)^T ----------
// Tile TM x 128, double-buffered async LDS staging, one barrier per K-iter.
// MODE 0: store bf16 (z==0 Q scaled by QSCALE; z==2 -> V transposed [b][h][d][s])
// MODE 1: +bias +fp32 residual -> fp32
// MODE 2: +bias, gelu -> bf16
// MODE 3: +bias +fp32 residual -> fp32 (final out)
template<int MODE, int TM>
__global__ __launch_bounds__(256, 4) void gemm_bt(const uint16_t* __restrict__ A,
    const uint16_t* __restrict__ Bt0,
    const float* __restrict__ bias,
    const float* __restrict__ resid,
    void* __restrict__ outp,
    uint16_t* __restrict__ vt_out,
    int N, int K, long bt_zstride, long out_zstride)
{
  constexpr int MI = TM/32;             // m-frags per wave
  __shared__ __align__(16) uint16_t As[2][TM][32];
  __shared__ __align__(16) uint16_t Bs[2][128][32];
  const uint16_t* Bt = Bt0 + (size_t)blockIdx.z * bt_zstride;
  int tid = threadIdx.x;
  int wave = tid>>6, ln = tid&63, lane16 = ln&15, quad = ln>>4;
  int m0 = blockIdx.x*TM, n0 = blockIdx.y*128;
  int wm = (wave>>1)*(MI*16), wn = (wave&1)*64;
  f32x4 zf = {0.f,0.f,0.f,0.f};
  f32x4 acc[MI][4];
  #pragma unroll
  for (int i=0;i<MI;i++)
    #pragma unroll
    for (int j=0;j<4;j++) acc[i][j]=zf;
  int ar = tid>>2;
  int ac = (tid&3)*8;
  const uint16_t* Arow0 = A  + (size_t)(m0+ar)*K    + ac;
  const uint16_t* Arow1 = A  + (size_t)(m0+ar+64)*K + ac;   // TM==128 only
  const uint16_t* Brow0 = Bt + (size_t)(n0+ar)*K    + ac;
  const uint16_t* Brow1 = Bt + (size_t)(n0+ar+64)*K + ac;

  auto stage = [&](int buf, int k0){
    char* lA = (char*)&As[buf][0][0] + wave*1024;
    char* lB = (char*)&Bs[buf][0][0] + wave*1024;
    gload16(Arow0 + k0, lA);
    if (TM==128) gload16(Arow1 + k0, lA + 4096);
    gload16(Brow0 + k0, lB);
    gload16(Brow1 + k0, lB + 4096);
  };

  int niter = K>>5;
  stage(0, 0);
  for (int s=0; s<niter; s++){
    __syncthreads();                    // drains staging of buf s&1
    if (s+1 < niter) stage((s+1)&1, (s+1)<<5);
    int buf = s&1;
    bf16x8 af[MI], bfr[4];
    #pragma unroll
    for (int mi=0;mi<MI;mi++) af[mi]  = *(const bf16x8*)&As[buf][wm+mi*16+lane16][quad*8];
    #pragma unroll
    for (int ni=0;ni<4;ni++)  bfr[ni] = *(const bf16x8*)&Bs[buf][wn+ni*16+lane16][quad*8];
    #pragma unroll
    for (int mi=0;mi<MI;mi++)
      #pragma unroll
      for (int ni=0;ni<4;ni++)
        acc[mi][ni] = __builtin_amdgcn_mfma_f32_16x16x32_bf16(af[mi], bfr[ni], acc[mi][ni], 0,0,0);
  }
  if (MODE==0 && blockIdx.z==2){
    #pragma unroll
    for (int mi=0;mi<MI;mi++){
      int mrow0 = m0 + wm + mi*16 + quad*4;
      int bb = mrow0 >> 11, s = mrow0 & 2047;
      #pragma unroll
      for (int ni=0;ni<4;ni++){
        int ncol = n0 + wn + ni*16 + lane16;
        int hh = ncol >> 6, dd = ncol & 63;
        ushort4 o4 = { f2bf(acc[mi][ni][0]), f2bf(acc[mi][ni][1]),
                       f2bf(acc[mi][ni][2]), f2bf(acc[mi][ni][3]) };
        *(ushort4*)(vt_out + ((size_t)((bb*NHEADS+hh)*HDIM + dd))*SEQ + s) = o4;
      }
    }
    return;
  }
  float oscale = (MODE==0 && blockIdx.z==0) ? QSCALE : 1.0f;
  #pragma unroll
  for (int mi=0;mi<MI;mi++){
    #pragma unroll
    for (int r=0;r<4;r++){
      int mrow = m0 + wm + mi*16 + quad*4 + r;
      #pragma unroll
      for (int ni=0;ni<4;ni++){
        int ncol = n0 + wn + ni*16 + lane16;
        float vv = acc[mi][ni][r];
        size_t idx = (size_t)mrow*N + ncol;
        if (MODE==0){
          ((uint16_t*)outp)[(size_t)blockIdx.z*out_zstride + idx] = f2bf(vv*oscale);
        } else if (MODE==1){
          ((float*)outp)[idx] = vv + bias[ncol] + resid[idx];
        } else if (MODE==2){
          float t = vv + bias[ncol];
          float u = 1.5957691216057308f*(t + 0.044715f*t*t*t);
          ((uint16_t*)outp)[idx] = f2bf(t / (1.f + __expf(-u)));
        } else {
          ((float*)outp)[idx] = vv + bias[ncol] + resid[idx];
        }
      }
    }
  }
}

// ---------- Flash attention v8: asm ds_read breaks the compiler drain -------
// r2/r3 post-mortem: the compiler inserts s_waitcnt vmcnt(0) before any C++
// ds_read that may alias an in-flight global_load_lds destination -> every
// step drained ALL prefetches (incl. 2-ahead), serializing at ~L2 latency
// (6000 cy/step vs ~800 of work). r4 (direct global frags) regressed: per-lane
// row-scattered 16B loads are TA-request-bound. Fix: keep r3's 3-buffer
// counted-vmcnt skeleton, but read K/V fragments via inline-asm ds_read_b128
// (invisible to alias analysis). Ordering guaranteed by OUR waits:
//   step s: vmcnt(8) [in-order retire: stage(s) done since stage(s+1)'s 8 are
//           newer]; s_barrier; issue stage(s+2);
//           16 asm ds_reads; lgkmcnt(8) [K-frags ready] -> QK MFMA;
//           lgkmcnt(0) [V-frags ready] -> softmax -> PV MFMA.
// sched_barrier(0) fences around the clusters (guide rule #18).
__global__ __launch_bounds__(128, 2) void attn_kernel(const uint16_t* __restrict__ q,
    const uint16_t* __restrict__ k, const uint16_t* __restrict__ vt,
    uint16_t* __restrict__ ctx)
{
  __shared__ __align__(16) uint16_t Ks[3][8][64][8];  // [buf][d-blk][kv][8]
  __shared__ __align__(16) uint16_t Vs[3][8][64][8];  // [buf][kv-blk][d][8]
  int tid = threadIdx.x;
  int wave = tid>>6, ln = tid&63, l32 = ln&31, h5 = ln>>5;
  // XCD-clustered decode: per-XCD K/V working set stays L2-hot
  int id  = blockIdx.x;        // 0..767
  int xcd = id & 7;
  int s_  = id >> 3;           // 0..95
  int p   = s_ & 15;           // q-pair index 0..15
  int g   = xcd*6 + (s_ >> 4); // (b,h) group 0..47, one XCD per group
  int h   = g % NHEADS, b = g / NHEADS;
  size_t kgbase = ((size_t)(b*SEQ + ln))*EMB + h*HDIM;       // + kv0*EMB + c*8
  size_t vgbase = ((size_t)((b*NHEADS + h)*HDIM + ln))*SEQ;  // + kv0 + c*8

  f32x16 o0, o1;               // O accum: col=q(l32), row=d-local
  float m_l, l_l;
  bf16x8 qb[4];                // Q B-operand frags: d = dm*16 + h5*8 + j
  int q0w, myq;

  auto stage = [&](int buf, int kv0){
    #pragma unroll
    for (int i=0;i<4;i++){
      int c = wave + 2*i;
      gload16(k  + kgbase + (size_t)kv0*EMB + c*8, &Ks[buf][c][0][0]);
      gload16(vt + vgbase + kv0 + c*8,             &Vs[buf][c][0][0]);
    }
  };
  auto init_tile = [&](int tile){
    q0w = tile*64 + wave*32;
    myq = q0w + l32;
    const uint16_t* qrow = q + ((size_t)(b*SEQ + myq))*EMB + h*HDIM + h5*8;
    #pragma unroll
    for (int dm=0;dm<4;dm++) qb[dm] = *(const bf16x8*)(qrow + dm*16);
    #pragma unroll
    for (int r=0;r<16;r++){ o0[r]=0.f; o1[r]=0.f; }
    m_l = -3.0e38f; l_l = 0.f;
  };
  auto writeout = [&](){
    float inv = 1.0f / l_l;
    // o reg r -> d = (r&3) + 8*(r>>2) + 4*h5  (+32 for o1), col q = myq
    uint16_t* crow = ctx + ((size_t)(b*SEQ + myq))*EMB + h*HDIM + 4*h5;
    #pragma unroll
    for (int rr=0; rr<4; rr++){
      ushort4 w0 = { f2bf(o0[4*rr+0]*inv), f2bf(o0[4*rr+1]*inv),
                     f2bf(o0[4*rr+2]*inv), f2bf(o0[4*rr+3]*inv) };
      *(ushort4*)(crow + rr*8) = w0;
      ushort4 w1 = { f2bf(o1[4*rr+0]*inv), f2bf(o1[4*rr+1]*inv),
                     f2bf(o1[4*rr+2]*inv), f2bf(o1[4*rr+3]*inv) };
      *(ushort4*)(crow + 32 + rr*8) = w1;
    }
  };
  auto compute = [&](int buf, int kv0, bool masked){
    // ---- bracketed asm LDS reads (K first, then V) ----
    __builtin_amdgcn_sched_barrier(0);
    bf16x8 ka0[4], ka1[4], va[4][2];
    #pragma unroll
    for (int dm=0;dm<4;dm++){
      ka0[dm] = lds_read16(&Ks[buf][dm*2+h5][l32][0]);
      ka1[dm] = lds_read16(&Ks[buf][dm*2+h5][32+l32][0]);
    }
    #pragma unroll
    for (int ks=0;ks<4;ks++){
      va[ks][0] = lds_read16(&Vs[buf][ks*2+h5][l32][0]);
      va[ks][1] = lds_read16(&Vs[buf][ks*2+h5][32+l32][0]);
    }
    asm volatile("s_waitcnt lgkmcnt(8)" ::: "memory");  // K-frags (oldest 8) done
    __builtin_amdgcn_sched_barrier(0);
    f32x16 st0, st1;           // S^T: row=kv-local, col=q(l32)
    #pragma unroll
    for (int r=0;r<16;r++){ st0[r]=0.f; st1[r]=0.f; }
    __builtin_amdgcn_s_setprio(1);
    #pragma unroll
    for (int dm=0;dm<4;dm++){
      st0 = __builtin_amdgcn_mfma_f32_32x32x16_bf16(ka0[dm], qb[dm], st0, 0,0,0);
      st1 = __builtin_amdgcn_mfma_f32_32x32x16_bf16(ka1[dm], qb[dm], st1, 0,0,0);
    }
    __builtin_amdgcn_s_setprio(0);
    asm volatile("s_waitcnt lgkmcnt(0)" ::: "memory");  // V-frags done
    __builtin_amdgcn_sched_barrier(0);
    if (masked){
      #pragma unroll
      for (int r=0;r<16;r++){
        int kvr = kv0 + (r&3) + 8*(r>>2) + 4*h5;   // C row->kv mapping
        if (kvr      > myq) st0[r] = -1e30f;
        if (kvr + 32 > myq) st1[r] = -1e30f;
      }
    }
    // row max over own 32 values (tree), then combine with partner half
    float t[8];
    #pragma unroll
    for (int r=0;r<8;r++)
      t[r] = fmaxf(fmaxf(st0[r], st0[r+8]), fmaxf(st1[r], st1[r+8]));
    t[0]=fmaxf(t[0],t[4]); t[1]=fmaxf(t[1],t[5]);
    t[2]=fmaxf(t[2],t[6]); t[3]=fmaxf(t[3],t[7]);
    float cm = fmaxf(fmaxf(t[0],t[1]), fmaxf(t[2],t[3]));
    cm = fmaxf(cm, __shfl_xor(cm, 32));          // combine with partner half
    // defer-max (T13): rescale only when max grew by > 6 (log2 domain)
    if (!__all(cm - m_l <= 6.0f)){
      float mn = fmaxf(m_l, cm);
      float alpha = __builtin_amdgcn_exp2f(m_l - mn);
      l_l *= alpha;
      #pragma unroll
      for (int r=0;r<16;r++){ o0[r]*=alpha; o1[r]*=alpha; }
      m_l = mn;
    }
    #pragma unroll
    for (int r=0;r<16;r++){
      st0[r] = __builtin_amdgcn_exp2f(st0[r] - m_l);
      st1[r] = __builtin_amdgcn_exp2f(st1[r] - m_l);
    }
    float s0=0.f, s1=0.f, s2=0.f, s3=0.f;
    #pragma unroll
    for (int r=0;r<16;r+=4){
      s0 += st0[r+0] + st1[r+0];
      s1 += st0[r+1] + st1[r+1];
      s2 += st0[r+2] + st1[r+2];
      s3 += st0[r+3] + st1[r+3];
    }
    float rs = (s0+s1)+(s2+s3);
    rs += __shfl_xor(rs, 32);                    // own + partner in all lanes
    l_l += rs;
    // P -> bf16 B-operand frags pbv[ks]: k = h5*8+j -> kv = ks*16 + h5*8 + j.
    // Own regs cover rows (0,1,2,3)+4h5 and (8..11)+4h5 of each 16-row slice;
    // the other half lives in the partner lane (same q, h5^1) -> shfl_xor(32).
    bf16x8 pbv[4];
    #pragma unroll
    for (int ks=0;ks<4;ks++){
      const int bs = (ks&1)*8;
      uint32_t c0,c1,c2,c3;
      if (ks < 2){
        c0 = cvt_pk_bf16(st0[bs+0], st0[bs+1]);  // rows (0,1)+base+4h5
        c1 = cvt_pk_bf16(st0[bs+2], st0[bs+3]);  // rows (2,3)+base+4h5
        c2 = cvt_pk_bf16(st0[bs+4], st0[bs+5]);  // rows (8,9)+base+4h5
        c3 = cvt_pk_bf16(st0[bs+6], st0[bs+7]);  // rows (10,11)+base+4h5
      } else {
        c0 = cvt_pk_bf16(st1[bs+0], st1[bs+1]);
        c1 = cvt_pk_bf16(st1[bs+2], st1[bs+3]);
        c2 = cvt_pk_bf16(st1[bs+4], st1[bs+5]);
        c3 = cvt_pk_bf16(st1[bs+6], st1[bs+7]);
      }
      // h5=0 lane needs partner's c0,c1 (kv+4..7); h5=1 needs partner's c2,c3
      uint32_t ya = (uint32_t)__shfl_xor((int)(h5 ? c0 : c2), 32);
      uint32_t yb = (uint32_t)__shfl_xor((int)(h5 ? c1 : c3), 32);
      union { uint32_t u[4]; bf16x8 v; } pu;
      pu.u[0] = h5 ? ya : c0;
      pu.u[1] = h5 ? yb : c1;
      pu.u[2] = h5 ? c2 : ya;
      pu.u[3] = h5 ? c3 : yb;
      pbv[ks] = pu.v;
    }
    __builtin_amdgcn_s_setprio(1);
    #pragma unroll
    for (int ks=0;ks<4;ks++){
      // A=V^T: row=d-local(l32), k = h5*8+j -> kv = ks*16+h5*8+j => kvblk=ks*2+h5
      o0 = __builtin_amdgcn_mfma_f32_32x32x16_bf16(va[ks][0], pbv[ks], o0, 0,0,0);
      o1 = __builtin_amdgcn_mfma_f32_32x32x16_bf16(va[ks][1], pbv[ks], o1, 0,0,0);
    }
    __builtin_amdgcn_s_setprio(0);
  };

  const int n0 = p + 1, ntot = 33;
  auto kv_of = [&](int sn){ int snl = (sn < n0) ? sn : sn - n0; return snl*64; };
  init_tile(p);
  stage(0, kv_of(0));
  stage(1, kv_of(1));
  for (int s=0; s<ntot; s++){
    // counted wait: stage(s) retired (stage(s+1)'s 8 newer ops cover vmcnt(8));
    // last step has no younger stage -> full drain.
    if (s+1 < ntot) { asm volatile("s_waitcnt vmcnt(8)" ::: "memory"); }
    else            { asm volatile("s_waitcnt vmcnt(0)" ::: "memory"); }
    __builtin_amdgcn_s_barrier();
    if (s+2 < ntot) stage((s+2)%3, kv_of(s+2));   // 2 phases ahead
    if (s == n0){ writeout(); init_tile(31 - p); }
    bool masked = (s == n0-1) || (s == ntot-1);
    compute(s%3, kv_of(s), masked);
  }
  writeout();
}

extern "C" void kernel_launch(void* const* d_in, const int* in_sizes, int n_in,
                              void* d_out, int out_size, void* d_ws, size_t ws_size,
                              hipStream_t stream) {
  const float* x     = (const float*)d_in[0];
  const float* ln1_s = (const float*)d_in[1];
  const float* ln1_b = (const float*)d_in[2];
  const float* wq    = (const float*)d_in[3];
  const float* wk    = (const float*)d_in[4];
  const float* wv    = (const float*)d_in[5];
  const float* wo    = (const float*)d_in[6];
  const float* bo    = (const float*)d_in[7];
  const float* ln2_s = (const float*)d_in[8];
  const float* ln2_b = (const float*)d_in[9];
  const float* w1    = (const float*)d_in[10];
  const float* b1    = (const float*)d_in[11];
  const float* w2    = (const float*)d_in[12];
  const float* b2    = (const float*)d_in[13];

  uint16_t* wqkv_t = (uint16_t*)d_ws;                 // 3 x [768][768]
  uint16_t* wo_t   = wqkv_t + 3*EMB*EMB;              // [768][768]
  uint16_t* w1_t   = wo_t   + EMB*EMB;                // [3072][768]
  uint16_t* w2_t   = w1_t   + (size_t)FFDIM*EMB;      // [768][3072]
  uint16_t* xn     = w2_t   + (size_t)EMB*FFDIM;      // [8192][768]
  uint16_t* qkv    = xn     + (size_t)NTOK*EMB;       // q,k normal; v slot unused
  uint16_t* ctx    = qkv    + (size_t)3*NTOK*EMB;     // [8192][768]
  uint16_t* hff    = qkv;                             // [8192][3072] overlays qkv+ctx
  float*    x1     = (float*)(ctx + (size_t)NTOK*EMB);// [8192][768] fp32
  uint16_t* vt     = (uint16_t*)(x1 + (size_t)NTOK*EMB); // [4][12][64][2048] V^T

  TPtrs tp;
  tp.src[0]=wq; tp.src[1]=wk; tp.src[2]=wv; tp.src[3]=wo; tp.src[4]=w1; tp.src[5]=w2;
  tp.dst[0]=wqkv_t; tp.dst[1]=wqkv_t+EMB*EMB; tp.dst[2]=wqkv_t+2*EMB*EMB;
  tp.dst[3]=wo_t; tp.dst[4]=w1_t; tp.dst[5]=w2_t;
  transpose_all<<<6912, dim3(32,8), 0, stream>>>(tp);

  ln_kernel<<<NTOK/4, 256, 0, stream>>>(x, ln1_s, ln1_b, xn);
  gemm_bt<0,128><<<dim3(NTOK/128, EMB/128, 3), 256, 0, stream>>>(
      xn, wqkv_t, nullptr, nullptr, qkv, vt, EMB, EMB,
      (long)EMB*EMB, (long)NTOK*EMB);
  attn_kernel<<<768, 128, 0, stream>>>(
      qkv, qkv + (size_t)NTOK*EMB, vt, ctx);
  // proj: TM=64 -> grid 128x6 = 768 blocks (3/CU)
  gemm_bt<1,64><<<dim3(NTOK/64, EMB/128, 1), 256, 0, stream>>>(
      ctx, wo_t, bo, x, x1, nullptr, EMB, EMB, 0, 0);
  ln_kernel<<<NTOK/4, 256, 0, stream>>>(x1, ln2_s, ln2_b, xn);
  gemm_bt<2,128><<<dim3(NTOK/128, FFDIM/128, 1), 256, 0, stream>>>(
      xn, w1_t, b1, nullptr, hff, nullptr, FFDIM, EMB, 0, 0);
  // FFN2: TM=64 -> grid 128x6 = 768 blocks (3/CU)
  gemm_bt<3,64><<<dim3(NTOK/64, EMB/128, 1), 256, 0, stream>>>(
      hff, w2_t, b2, x1, d_out, nullptr, EMB, FFDIM, 0, 0);
}